// Round 12
// baseline (107.327 us; speedup 1.0000x reference)
//
#include <hip/hip_runtime.h>

#define HIDDEN 4096
#define RANK   256
#define G      16     // HIDDEN / RANK
#define TWX    8      // tokens per wave in expand (wave = 8 tok x 64 cols)

typedef _Float16 h2d __attribute__((ext_vector_type(2)));
typedef float    f4v __attribute__((ext_vector_type(4)));

__device__ __forceinline__ unsigned int pkf16(float a, float b) {
    auto h = __builtin_amdgcn_cvt_pkrtz(a, b);
    return __builtin_bit_cast(unsigned int, h);
}
__device__ __forceinline__ float dot2(unsigned int a, unsigned int b, float c) {
    return __builtin_amdgcn_fdot2(__builtin_bit_cast(h2d, a),
                                  __builtin_bit_cast(h2d, b), c, false);
}

// ---------------------------------------------------------------------------
// k1: compress (+ fused M-pack in the last 128 blocks).
//   compress: thread = one float4 of comp; writes DENSE f16 pair-pack
//             comp_pk[t*64 + r4] = {pk(r0,r1), pk(r2,r3)}.
//   pack:     Mp[pr*256 + k] = {f16 M[2pr][k], f16 M[2pr+1][k]}  (128 KB).
// ---------------------------------------------------------------------------
#define NCOMPB 4096   // compress blocks (T*64/256)
#define NPACKB 128    // pack blocks

__global__ __launch_bounds__(256)
void mora_compress(const float* __restrict__ x,      // [T, HIDDEN]
                   const float* __restrict__ Mg,     // [RANK, RANK]
                   uint2* __restrict__ comp_pk,      // [T][64]
                   unsigned int* __restrict__ Mp)    // [128][256]
{
    if (blockIdx.x >= NCOMPB) {
        const int idx = (blockIdx.x - NCOMPB) * 256 + threadIdx.x;  // 0..32767
        const int pr  = idx >> 8;
        const int k   = idx & 255;
        Mp[idx] = pkf16(Mg[(size_t)(2 * pr) * RANK + k],
                        Mg[(size_t)(2 * pr + 1) * RANK + k]);
        return;
    }

    const long i  = (long)blockIdx.x * 256 + threadIdx.x;  // 0..T*64-1
    const long t  = i >> 6;
    const int  r4 = (int)(i & 63);

    const float4* xr = (const float4*)(x + t * HIDDEN) + r4;
    float4 e = xr[0];
    float4 o = xr[64];
    #pragma unroll
    for (int gi = 1; gi < G / 2; ++gi) {      // two independent chains (ILP)
        const float4 a = xr[(2 * gi) * 64];
        const float4 b = xr[(2 * gi + 1) * 64];
        e.x += a.x; e.y += a.y; e.z += a.z; e.w += a.w;
        o.x += b.x; o.y += b.y; o.z += b.z; o.w += b.w;
    }
    e.x += o.x; e.y += o.y; e.z += o.z; e.w += o.w;
    comp_pk[t * 64 + r4] = make_uint2(pkf16(e.x, e.y), pkf16(e.z, e.w));
}

// ---------------------------------------------------------------------------
// k2: expand, 4-way column split. Wave = 8 tokens x 64 columns (1 col/lane):
//     M footprint 32 KB/wave -> 256 MB total L2 traffic, 8192 waves (full
//     TLP). dot2 accumulate, NT coalesced splat stores.
// ---------------------------------------------------------------------------
__global__ __launch_bounds__(256)
void mora_expand(const uint2* __restrict__ comp_pk,     // [T][64]
                 const unsigned int* __restrict__ Mp,   // [128][256]
                 float* __restrict__ out)               // [T, HIDDEN]
{
    __shared__ float ost[4][64];            // per-wave private, no barriers

    const int  tid  = threadIdx.x;
    const int  w    = tid >> 6;
    const int  l    = tid & 63;
    const int  wid  = blockIdx.x * 4 + w;   // 0..8191
    const int  q    = wid & 3;              // column quarter 0..3
    const long tok0 = (long)(wid >> 2) * TWX;
    const int  kcol = (q << 6) + l;         // this lane's single column

    // comp pairs: lane l holds pair 2l (rows 4l,4l+1) and 2l+1 (rows 4l+2,4l+3)
    unsigned int cp0[TWX], cp1[TWX];
    #pragma unroll
    for (int t = 0; t < TWX; ++t) {
        const uint2 c = comp_pk[(tok0 + t) * 64 + l];   // coalesced 512 B/wave
        cp0[t] = c.x;
        cp1[t] = c.y;
    }

    float acc[TWX];
    #pragma unroll
    for (int t = 0; t < TWX; ++t) acc[t] = 0.f;

    // pair-rows 4i..4i+3 per iter; lane reads its single column (dword each)
    #pragma unroll 4
    for (int i = 0; i < 32; ++i) {
        const unsigned m0 = Mp[(4 * i + 0) * 256 + kcol];   // coalesced 256 B
        const unsigned m1 = Mp[(4 * i + 1) * 256 + kcol];
        const unsigned m2 = Mp[(4 * i + 2) * 256 + kcol];
        const unsigned m3 = Mp[(4 * i + 3) * 256 + kcol];
        #pragma unroll
        for (int t = 0; t < TWX; ++t) {
            const unsigned s0 = (unsigned)__builtin_amdgcn_readlane((int)cp0[t], 2 * i);
            const unsigned s1 = (unsigned)__builtin_amdgcn_readlane((int)cp1[t], 2 * i);
            const unsigned s2 = (unsigned)__builtin_amdgcn_readlane((int)cp0[t], 2 * i + 1);
            const unsigned s3 = (unsigned)__builtin_amdgcn_readlane((int)cp1[t], 2 * i + 1);
            acc[t] = dot2(s0, m0, acc[t]);
            acc[t] = dot2(s1, m1, acc[t]);
            acc[t] = dot2(s2, m2, acc[t]);
            acc[t] = dot2(s3, m3, acc[t]);
        }
    }

    // restage per wave, then NT coalesced splat stores (4 KiB/token quarter)
    #pragma unroll
    for (int t = 0; t < TWX; ++t) {
        ost[w][l] = acc[t];
        f4v* oq = (f4v*)(out + (tok0 + t) * HIDDEN) + (q << 8);
        #pragma unroll
        for (int s = 0; s < 4; ++s) {
            const float v = ost[w][(s << 4) + (l >> 2)];  // 4-lane bcast, no conflict
            const f4v sp = {v, v, v, v};
            __builtin_nontemporal_store(sp, oq + (s << 6) + l);
        }
    }
}

extern "C" void kernel_launch(void* const* d_in, const int* in_sizes, int n_in,
                              void* d_out, int out_size, void* d_ws, size_t ws_size,
                              hipStream_t stream) {
    const float* x = (const float*)d_in[0];
    const float* M = (const float*)d_in[1];
    float* out     = (float*)d_out;

    unsigned int* Mp      = (unsigned int*)d_ws;               // 128 KiB
    uint2*        comp_pk = (uint2*)((char*)d_ws + 131072);    // 8 MiB

    const int T = in_sizes[0] / HIDDEN;     // 16384 tokens

    hipLaunchKernelGGL(mora_compress, dim3(NCOMPB + NPACKB), dim3(256),
                       0, stream, x, M, comp_pk, Mp);
    hipLaunchKernelGGL(mora_expand, dim3(T / TWX * 4 / 4), dim3(256), 0, stream,
                       comp_pk, Mp, out);
}

// Round 13
// 102.011 us; speedup vs baseline: 1.0521x; 1.0521x over previous
//
#include <hip/hip_runtime.h>

#define HIDDEN 4096
#define RANK   256
#define G      16     // HIDDEN / RANK
#define TWX    8      // tokens per wave in expand (wave = 8 tok x 64 cols)

typedef _Float16 h2d __attribute__((ext_vector_type(2)));
typedef float    f4v __attribute__((ext_vector_type(4)));

__device__ __forceinline__ unsigned int pkf16(float a, float b) {
    auto h = __builtin_amdgcn_cvt_pkrtz(a, b);
    return __builtin_bit_cast(unsigned int, h);
}
__device__ __forceinline__ float dot2(unsigned int a, unsigned int b, float c) {
    return __builtin_amdgcn_fdot2(__builtin_bit_cast(h2d, a),
                                  __builtin_bit_cast(h2d, b), c, false);
}

// ---------------------------------------------------------------------------
// k1: compress (+ fused M-pack in the last 128 blocks).
// ---------------------------------------------------------------------------
#define NCOMPB 4096   // compress blocks (T*64/256)
#define NPACKB 128    // pack blocks

__global__ __launch_bounds__(256)
void mora_compress(const float* __restrict__ x,      // [T, HIDDEN]
                   const float* __restrict__ Mg,     // [RANK, RANK]
                   uint2* __restrict__ comp_pk,      // [T][64]
                   unsigned int* __restrict__ Mp)    // [128][256]
{
    if (blockIdx.x >= NCOMPB) {
        const int idx = (blockIdx.x - NCOMPB) * 256 + threadIdx.x;  // 0..32767
        const int pr  = idx >> 8;
        const int k   = idx & 255;
        Mp[idx] = pkf16(Mg[(size_t)(2 * pr) * RANK + k],
                        Mg[(size_t)(2 * pr + 1) * RANK + k]);
        return;
    }

    const long i  = (long)blockIdx.x * 256 + threadIdx.x;  // 0..T*64-1
    const long t  = i >> 6;
    const int  r4 = (int)(i & 63);

    const float4* xr = (const float4*)(x + t * HIDDEN) + r4;
    float4 e = xr[0];
    float4 o = xr[64];
    #pragma unroll
    for (int gi = 1; gi < G / 2; ++gi) {      // two independent chains (ILP)
        const float4 a = xr[(2 * gi) * 64];
        const float4 b = xr[(2 * gi + 1) * 64];
        e.x += a.x; e.y += a.y; e.z += a.z; e.w += a.w;
        o.x += b.x; o.y += b.y; o.z += b.z; o.w += b.w;
    }
    e.x += o.x; e.y += o.y; e.z += o.z; e.w += o.w;
    comp_pk[t * 64 + r4] = make_uint2(pkf16(e.x, e.y), pkf16(e.z, e.w));
}

// ---------------------------------------------------------------------------
// k2: expand. 512-thr block = 8 waves sharing ONE column quarter; the 32 KiB
//     Mp quarter is staged to LDS once per block (uint4 coalesced, 32 MB
//     total L2 traffic — 8x less than R12), one barrier, then the barrier-
//     free per-wave loop: M via conflict-free ds_read_b32, comp via
//     registers+readlane, NT coalesced splat stores.
// ---------------------------------------------------------------------------
#define ENTH 512

__global__ __launch_bounds__(ENTH)
void mora_expand(const uint2* __restrict__ comp_pk,     // [T][64]
                 const unsigned int* __restrict__ Mp,   // [128][256]
                 float* __restrict__ out)               // [T, HIDDEN]
{
    __shared__ unsigned int Mlds[128 * 64];   // 32 KiB: this block's quarter
    __shared__ float ost[ENTH / 64][64];      // 2 KiB, per-wave private

    const int  tid  = threadIdx.x;
    const int  w    = tid >> 6;               // wave 0..7
    const int  l    = tid & 63;
    const int  q    = blockIdx.x & 3;         // column quarter
    const long tok0 = ((long)(blockIdx.x >> 2) * 8 + w) * TWX;

    // ---- stage M quarter -> LDS (2048 uint4, coalesced, linear dst) ----
    {
        const uint4* src = (const uint4*)Mp;  // row = 64 uint4
        uint4* dst = (uint4*)Mlds;
        #pragma unroll
        for (int i = 0; i < 4; ++i) {
            const int p  = tid + (i << 9);    // 0..2047
            const int pr = p >> 4;            // pair-row
            const int c4 = p & 15;            // uint4 within quarter row
            dst[p] = src[pr * 64 + (q << 4) + c4];
        }
    }

    // ---- comp -> registers (issued before barrier; latency hides) ----
    unsigned int cp0[TWX], cp1[TWX];
    #pragma unroll
    for (int t = 0; t < TWX; ++t) {
        const uint2 c = comp_pk[(tok0 + t) * 64 + l];   // coalesced 512 B/wave
        cp0[t] = c.x;
        cp1[t] = c.y;
    }
    __syncthreads();

    float acc[TWX];
    #pragma unroll
    for (int t = 0; t < TWX; ++t) acc[t] = 0.f;

    // ---- main loop: pair-rows 4i..4i+3; M from LDS (free 2-way b32) ----
    const unsigned int* Ml = Mlds + l;
    #pragma unroll 4
    for (int i = 0; i < 32; ++i) {
        const unsigned m0 = Ml[(4 * i + 0) << 6];
        const unsigned m1 = Ml[(4 * i + 1) << 6];
        const unsigned m2 = Ml[(4 * i + 2) << 6];
        const unsigned m3 = Ml[(4 * i + 3) << 6];
        #pragma unroll
        for (int t = 0; t < TWX; ++t) {
            const unsigned s0 = (unsigned)__builtin_amdgcn_readlane((int)cp0[t], 2 * i);
            const unsigned s1 = (unsigned)__builtin_amdgcn_readlane((int)cp1[t], 2 * i);
            const unsigned s2 = (unsigned)__builtin_amdgcn_readlane((int)cp0[t], 2 * i + 1);
            const unsigned s3 = (unsigned)__builtin_amdgcn_readlane((int)cp1[t], 2 * i + 1);
            acc[t] = dot2(s0, m0, acc[t]);
            acc[t] = dot2(s1, m1, acc[t]);
            acc[t] = dot2(s2, m2, acc[t]);
            acc[t] = dot2(s3, m3, acc[t]);
        }
    }

    // ---- restage per wave, NT coalesced splat stores (4 KiB/token-quarter)
    #pragma unroll
    for (int t = 0; t < TWX; ++t) {
        ost[w][l] = acc[t];
        f4v* oq = (f4v*)(out + (tok0 + t) * HIDDEN) + (q << 8);
        #pragma unroll
        for (int s = 0; s < 4; ++s) {
            const float v = ost[w][(s << 4) + (l >> 2)];  // 4-lane bcast, free
            const f4v sp = {v, v, v, v};
            __builtin_nontemporal_store(sp, oq + (s << 6) + l);
        }
    }
}

extern "C" void kernel_launch(void* const* d_in, const int* in_sizes, int n_in,
                              void* d_out, int out_size, void* d_ws, size_t ws_size,
                              hipStream_t stream) {
    const float* x = (const float*)d_in[0];
    const float* M = (const float*)d_in[1];
    float* out     = (float*)d_out;

    unsigned int* Mp      = (unsigned int*)d_ws;               // 128 KiB
    uint2*        comp_pk = (uint2*)((char*)d_ws + 131072);    // 8 MiB

    const int T = in_sizes[0] / HIDDEN;     // 16384 tokens

    hipLaunchKernelGGL(mora_compress, dim3(NCOMPB + NPACKB), dim3(256),
                       0, stream, x, M, comp_pk, Mp);
    // blocks = (token-octets / 8 waves) * 4 quarters = (T/8/8)*4 = T/16
    hipLaunchKernelGGL(mora_expand, dim3(T / 16), dim3(ENTH), 0, stream,
                       comp_pk, Mp, out);
}

// Round 14
// 96.032 us; speedup vs baseline: 1.1176x; 1.0623x over previous
//
#include <hip/hip_runtime.h>

#define HIDDEN 4096
#define RANK   256
#define G      16     // HIDDEN / RANK
#define NTH    1024   // 16 waves, 1 block/CU (LDS-forced)
#define TB     4      // tokens per wave (16 waves * 4 = 64 tokens/block)

typedef _Float16 h2d __attribute__((ext_vector_type(2)));
typedef float    f4v __attribute__((ext_vector_type(4)));

__device__ __forceinline__ unsigned int pkf16(float a, float b) {
    auto h = __builtin_amdgcn_cvt_pkrtz(a, b);
    return __builtin_bit_cast(unsigned int, h);
}
__device__ __forceinline__ float dot2(unsigned int a, unsigned int b, float c) {
    return __builtin_amdgcn_fdot2(__builtin_bit_cast(h2d, a),
                                  __builtin_bit_cast(h2d, b), c, false);
}

// ---------------------------------------------------------------------------
// pack: Mp[pr*256 + k] = {f16 M[2pr][k], f16 M[2pr+1][k]}   (128 KB, once)
// ---------------------------------------------------------------------------
__global__ __launch_bounds__(256)
void mora_pack(const float* __restrict__ Mg, unsigned int* __restrict__ Mp) {
    const int idx = blockIdx.x * 256 + threadIdx.x;    // 0..32767
    const int pr  = idx >> 8;
    const int k   = idx & 255;
    Mp[idx] = pkf16(Mg[(size_t)(2 * pr) * RANK + k],
                    Mg[(size_t)(2 * pr + 1) * RANK + k]);
}

// ---------------------------------------------------------------------------
// fused: block = 64 tokens, full M in LDS (staged once, 32 MB total L2).
// Wave owns 4 tokens end-to-end: compress in registers BEFORE the single
// barrier (x-reads hide M staging), then full-width expand (lane owns cols
// 4l..4l+3; M rows via conflict-free ds_read_b128; comp via readlane->dot2),
// per-wave restage, NT coalesced splat stores. Read and write HBM streams
// interleave continuously across the block population.
// Dynamic LDS: [0,131072) Mp f16-pairs; [131072,147456) ostage f32[16][256].
// ---------------------------------------------------------------------------
__global__ __launch_bounds__(NTH)
void mora_fused(const float* __restrict__ x,          // [T, HIDDEN]
                const unsigned int* __restrict__ Mp,  // [128][256] f16 pairs
                float* __restrict__ out)              // [T, HIDDEN]
{
    extern __shared__ unsigned char smem[];
    unsigned int* Ml = (unsigned int*)smem;            // [128][256]
    float* ostage    = (float*)(smem + 131072);        // [16][256]

    const int  tid  = threadIdx.x;
    const int  w    = tid >> 6;    // wave 0..15
    const int  l    = tid & 63;    // lane
    const long tok0 = (long)blockIdx.x * (16 * TB) + (long)w * TB;

    // ---- stage full packed M -> LDS (8192 uint4, coalesced, linear) ----
    {
        const uint4* src = (const uint4*)Mp;
        uint4* dst = (uint4*)Ml;
        #pragma unroll
        for (int i = 0; i < 8; ++i)
            dst[tid + (i << 10)] = src[tid + (i << 10)];
    }

    // ---- compress (no LDS): lane owns rows 4l..4l+3 = pairs 2l, 2l+1 ----
    unsigned int cp0[TB], cp1[TB];
    #pragma unroll
    for (int t = 0; t < TB; ++t) {
        const float4* xr = (const float4*)(x + (tok0 + t) * HIDDEN) + l;
        float4 e = xr[0];
        float4 o = xr[64];
        #pragma unroll
        for (int gi = 1; gi < G / 2; ++gi) {
            const float4 a = xr[(2 * gi) * 64];
            const float4 b = xr[(2 * gi + 1) * 64];
            e.x += a.x; e.y += a.y; e.z += a.z; e.w += a.w;
            o.x += b.x; o.y += b.y; o.z += b.z; o.w += b.w;
        }
        e.x += o.x; e.y += o.y; e.z += o.z; e.w += o.w;
        cp0[t] = pkf16(e.x, e.y);
        cp1[t] = pkf16(e.z, e.w);
    }
    __syncthreads();   // M staged; comp in registers

    // ---- expand: acc[t][c] = sum_r comp[t][r] * M[r][4l+c] ----
    float acc[TB][4];
    #pragma unroll
    for (int t = 0; t < TB; ++t) {
        acc[t][0] = 0.f; acc[t][1] = 0.f; acc[t][2] = 0.f; acc[t][3] = 0.f;
    }

    const uint4* Ml4 = (const uint4*)Ml + l;   // pair-row stride = 64 uint4
    #pragma unroll 2
    for (int i = 0; i < 32; ++i) {
        const uint4 m0 = Ml4[(4 * i + 0) << 6];   // 1 KiB b128, conflict-free
        const uint4 m1 = Ml4[(4 * i + 1) << 6];
        const uint4 m2 = Ml4[(4 * i + 2) << 6];
        const uint4 m3 = Ml4[(4 * i + 3) << 6];
        #pragma unroll
        for (int t = 0; t < TB; ++t) {
            const unsigned s0 = (unsigned)__builtin_amdgcn_readlane((int)cp0[t], 2 * i);
            const unsigned s1 = (unsigned)__builtin_amdgcn_readlane((int)cp1[t], 2 * i);
            const unsigned s2 = (unsigned)__builtin_amdgcn_readlane((int)cp0[t], 2 * i + 1);
            const unsigned s3 = (unsigned)__builtin_amdgcn_readlane((int)cp1[t], 2 * i + 1);
            acc[t][0] = dot2(s0, m0.x, acc[t][0]);
            acc[t][1] = dot2(s0, m0.y, acc[t][1]);
            acc[t][2] = dot2(s0, m0.z, acc[t][2]);
            acc[t][3] = dot2(s0, m0.w, acc[t][3]);
            acc[t][0] = dot2(s1, m1.x, acc[t][0]);
            acc[t][1] = dot2(s1, m1.y, acc[t][1]);
            acc[t][2] = dot2(s1, m1.z, acc[t][2]);
            acc[t][3] = dot2(s1, m1.w, acc[t][3]);
            acc[t][0] = dot2(s2, m2.x, acc[t][0]);
            acc[t][1] = dot2(s2, m2.y, acc[t][1]);
            acc[t][2] = dot2(s2, m2.z, acc[t][2]);
            acc[t][3] = dot2(s2, m2.w, acc[t][3]);
            acc[t][0] = dot2(s3, m3.x, acc[t][0]);
            acc[t][1] = dot2(s3, m3.y, acc[t][1]);
            acc[t][2] = dot2(s3, m3.z, acc[t][2]);
            acc[t][3] = dot2(s3, m3.w, acc[t][3]);
        }
    }

    // ---- per-wave restage + NT coalesced splat stores (16 KiB/token) ----
    float* ost = ostage + w * RANK;
    #pragma unroll
    for (int t = 0; t < TB; ++t) {
        ((float4*)ost)[l] =
            make_float4(acc[t][0], acc[t][1], acc[t][2], acc[t][3]);
        f4v* orow = (f4v*)(out + (tok0 + t) * HIDDEN);
        #pragma unroll
        for (int s = 0; s < 16; ++s) {
            const float v = ost[(s << 4) + (l >> 2)];  // 4-lane bcast, free
            const f4v sp = {v, v, v, v};
            __builtin_nontemporal_store(sp, orow + (s << 6) + l);
        }
    }
}

extern "C" void kernel_launch(void* const* d_in, const int* in_sizes, int n_in,
                              void* d_out, int out_size, void* d_ws, size_t ws_size,
                              hipStream_t stream) {
    const float* x = (const float*)d_in[0];
    const float* M = (const float*)d_in[1];
    float* out     = (float*)d_out;

    unsigned int* Mp = (unsigned int*)d_ws;    // 128 KiB packed M

    const int T = in_sizes[0] / HIDDEN;        // 16384 tokens
    const int smem_bytes = 147456;             // 128 KiB M + 16 KiB ostage

    (void)hipFuncSetAttribute((const void*)mora_fused,
                              hipFuncAttributeMaxDynamicSharedMemorySize,
                              smem_bytes);

    hipLaunchKernelGGL(mora_pack, dim3(128), dim3(256), 0, stream, M, Mp);
    hipLaunchKernelGGL(mora_fused, dim3(T / (16 * TB)), dim3(NTH), smem_bytes,
                       stream, x, Mp, out);
}